// Round 11
// baseline (228.480 us; speedup 1.0000x reference)
//
#include <hip/hip_runtime.h>

#define NP   8732
#define NOBJ 32
#define NB   256
#define NT   1024
#define PPT  9            // ceil(8732/1024)
#define NW   (NT/64)      // 16 waves
#define KA2  137          // ceil(8732/64)

__device__ __forceinline__ float sl1(float d){
    float ad = fabsf(d);
    return ad < 1.0f ? 0.5f * d * d : ad - 0.5f;
}

// r9 post-mortem: per-thread prior ARRAYS (9- or 3-element) give ~2.8x VALU
// inflation at any VGPR count; chunking regressed (extra wave-reduces cost
// ~0.6us each). This version: array-free loops, tiny live sets.
//   A1: i-outer/t-inner, per-prior best-truth in 2 regs.
//   A2: wave-per-2-truths, lanes scan priors coalesced; 32 reduces total.
__global__ __attribute__((amdgpu_flat_work_group_size(NT, NT),
                          amdgpu_waves_per_eu(4, 4))) void mbox_main(
    const float* __restrict__ loc_data,   // [B,P,4]
    const float* __restrict__ conf_data,  // [B,P,2]
    const float* __restrict__ priors,     // [P,4] cx,cy,w,h
    const float* __restrict__ targets,    // [B,NOBJ,5] x1,y1,x2,y2,label
    float* __restrict__ out_part)         // [B,4] lossl, lossc, npos, pad
{
    const int b    = blockIdx.x;
    const int tid  = threadIdx.x;
    const int lane = tid & 63;
    const int wid  = tid >> 6;

    __shared__ float s_tx1[NOBJ], s_ty1[NOBJ], s_tx2[NOBJ], s_ty2[NOBJ],
                     s_ta[NOBJ], s_tl[NOBJ];
    __shared__ float s_bto[NP];
    __shared__ unsigned char s_bti[NP];
    __shared__ int s_bp[NOBJ];
    __shared__ unsigned long long s_red64[NW];
    __shared__ float s_redf[NW], s_redf2[NW];
    __shared__ int s_redi[NW];

    // ---- load truths ----
    if (tid < NOBJ){
        const float* tp = targets + ((size_t)b * NOBJ + tid) * 5;
        float x1 = tp[0], y1 = tp[1], x2 = tp[2], y2 = tp[3];
        s_tx1[tid] = x1; s_ty1[tid] = y1; s_tx2[tid] = x2; s_ty2[tid] = y2;
        s_ta[tid]  = (x2 - x1) * (y2 - y1);
        s_tl[tid]  = tp[4];
    }
    __syncthreads();

    // ---- A1: per-prior best truth (i outer, t inner; no arrays) ----
    #pragma unroll 1
    for (int i = 0; i < PPT; ++i){
        int p = tid + i * NT;
        if (p < NP){
            float4 pr = reinterpret_cast<const float4*>(priors)[p];
            float hx  = pr.z * 0.5f, hy = pr.w * 0.5f;
            float px1 = pr.x - hx, py1 = pr.y - hy;
            float px2 = pr.x + hx, py2 = pr.y + hy;
            float pa  = (px2 - px1) * (py2 - py1);
            float bto = -1.0f; int bti = 0;
            #pragma unroll 4
            for (int t = 0; t < NOBJ; ++t){
                float lx = fmaxf(s_tx1[t], px1);
                float ly = fmaxf(s_ty1[t], py1);
                float rx = fminf(s_tx2[t], px2);
                float ry = fminf(s_ty2[t], py2);
                float w  = fmaxf(rx - lx, 0.0f);
                float h  = fmaxf(ry - ly, 0.0f);
                float inter = w * h;
                float den   = s_ta[t] + pa - inter;
                float iou   = inter / den;           // exact: argmax-safe
                if (iou > bto){ bto = iou; bti = t; }  // first occurrence on tie
            }
            s_bto[p] = bto;
            s_bti[p] = (unsigned char)bti;
        }
    }

    // ---- A2: per-truth best prior (one wave per 2 truths) ----
    {
        const int t0 = 2 * wid, t1 = 2 * wid + 1;
        float atx1 = s_tx1[t0], aty1 = s_ty1[t0], atx2 = s_tx2[t0],
              aty2 = s_ty2[t0], ata = s_ta[t0];
        float btx1 = s_tx1[t1], bty1 = s_ty1[t1], btx2 = s_tx2[t1],
              bty2 = s_ty2[t1], bta = s_ta[t1];
        float bv0 = -1.0f, bv1 = -1.0f;
        int   bp0 = 0,     bp1 = 0;
        #pragma unroll 2
        for (int k = 0; k < KA2; ++k){
            int p = lane + (k << 6);
            if (p < NP){
                float4 pr = reinterpret_cast<const float4*>(priors)[p];
                float hx  = pr.z * 0.5f, hy = pr.w * 0.5f;
                float px1 = pr.x - hx, py1 = pr.y - hy;
                float px2 = pr.x + hx, py2 = pr.y + hy;
                float pa  = (px2 - px1) * (py2 - py1);
                {
                    float lx = fmaxf(atx1, px1), ly = fmaxf(aty1, py1);
                    float rx = fminf(atx2, px2), ry = fminf(aty2, py2);
                    float w  = fmaxf(rx - lx, 0.0f), h = fmaxf(ry - ly, 0.0f);
                    float inter = w * h;
                    float iou = inter / (ata + pa - inter);
                    if (iou > bv0){ bv0 = iou; bp0 = p; }  // ascending p per lane
                }
                {
                    float lx = fmaxf(btx1, px1), ly = fmaxf(bty1, py1);
                    float rx = fminf(btx2, px2), ry = fminf(bty2, py2);
                    float w  = fmaxf(rx - lx, 0.0f), h = fmaxf(ry - ly, 0.0f);
                    float inter = w * h;
                    float iou = inter / (bta + pa - inter);
                    if (iou > bv1){ bv1 = iou; bp1 = p; }
                }
            }
        }
        // key packs (value, smaller-p-wins); butterfly max over 64 lanes
        unsigned long long k0 = ((unsigned long long)__float_as_uint(bv0) << 32)
                              | (unsigned)(NP - 1 - bp0);
        unsigned long long k1 = ((unsigned long long)__float_as_uint(bv1) << 32)
                              | (unsigned)(NP - 1 - bp1);
        #pragma unroll
        for (int off = 32; off > 0; off >>= 1){
            unsigned long long o0 = __shfl_xor(k0, off);
            unsigned long long o1 = __shfl_xor(k1, off);
            if (o0 > k0) k0 = o0;
            if (o1 > k1) k1 = o1;
        }
        if (lane == 0){
            s_bp[t0] = NP - 1 - (int)(k0 & 0xffffffffu);
            s_bp[t1] = NP - 1 - (int)(k1 & 0xffffffffu);
        }
    }
    __syncthreads();

    // ---- sequential override (ascending t: last write wins on dup) ----
    if (tid == 0){
        for (int t = 0; t < NOBJ; ++t){
            int p = s_bp[t];
            s_bto[p] = 2.0f;
            s_bti[p] = (unsigned char)t;
        }
    }
    __syncthreads();

    // ---- Phase C: ce / loc loss / rank ----
    float lossl = 0.0f, sumce = 0.0f;
    int npos = 0;
    unsigned rb_[PPT];
    #pragma unroll
    for (int i = 0; i < PPT; ++i){
        int p = tid + i * NT;
        float rank = 0.0f;
        if (p < NP){
            float ov = s_bto[p];
            int   t  = s_bti[p];
            bool pos = !(ov < 0.5f);
            float2 c = reinterpret_cast<const float2*>(conf_data)[(size_t)b * NP + p];
            float m   = fmaxf(c.x, c.y);
            float lse = m + logf(expf(c.x - m) + expf(c.y - m));
            if (pos){
                int cls = (int)s_tl[t] + 1;
                float g = (cls >= 1) ? c.y : c.x;
                float ce = lse - g;
                ++npos;
                sumce += ce;
                float4 l  = reinterpret_cast<const float4*>(loc_data)[(size_t)b * NP + p];
                float4 pr = reinterpret_cast<const float4*>(priors)[p];
                float mx1 = s_tx1[t], my1 = s_ty1[t], mx2 = s_tx2[t], my2 = s_ty2[t];
                float gcx = ((mx1 + mx2) * 0.5f - pr.x) / (0.1f * pr.z);
                float gcy = ((my1 + my2) * 0.5f - pr.y) / (0.1f * pr.w);
                float gw  = logf((mx2 - mx1) / pr.z) / 0.2f;
                float gh  = logf((my2 - my1) / pr.w) / 0.2f;
                lossl += sl1(l.x - gcx) + sl1(l.y - gcy)
                       + sl1(l.z - gw)  + sl1(l.w - gh);
                rank = 0.0f;                       // positives zeroed in ranking
            } else {
                rank = lse - c.x;                  // ce with class 0 (>= 0)
            }
        }
        rb_[i] = __float_as_uint(rank);            // rank >= 0 -> bits ordered
    }

    // ---- reduce npos / sumce / lossl ----
    #pragma unroll
    for (int off = 32; off > 0; off >>= 1){
        npos  += __shfl_xor(npos,  off);
        sumce += __shfl_xor(sumce, off);
        lossl += __shfl_xor(lossl, off);
    }
    if (lane == 0){ s_redi[wid] = npos; s_redf[wid] = sumce; s_redf2[wid] = lossl; }
    __syncthreads();
    int npos_tot = 0; float sumce_tot = 0.0f, lossl_tot = 0.0f;
    #pragma unroll
    for (int j = 0; j < NW; ++j){
        npos_tot  += s_redi[j];
        sumce_tot += s_redf[j];
        lossl_tot += s_redf2[j];
    }
    __syncthreads();

    // ---- Phase D: k-th largest rank via 2-bit radix binary search ----
    int k = 3 * npos_tot; if (k > NP - 1) k = NP - 1;
    unsigned vk = 0u;
    for (int bit = 30; bit >= 0; bit = (bit == 30) ? 28 : bit - 2){
        unsigned c1, c2, c3;
        bool pair = (bit != 30);
        if (pair){
            c1 = vk | (1u << bit); c2 = vk | (2u << bit); c3 = vk | (3u << bit);
        } else {
            c1 = vk | (1u << 30); c2 = 0xffffffffu; c3 = 0xffffffffu;
        }
        unsigned long long pc = 0ull;
        #pragma unroll
        for (int i = 0; i < PPT; ++i){
            unsigned u = rb_[i];
            pc += (u >= c1) ? 1ull : 0ull;
            pc += (u >= c2) ? (1ull << 21) : 0ull;
            pc += (u >= c3) ? (1ull << 42) : 0ull;
        }
        #pragma unroll
        for (int off = 32; off > 0; off >>= 1)
            pc += __shfl_xor(pc, off);
        if (lane == 0) s_red64[wid] = pc;
        __syncthreads();
        unsigned long long tot = 0ull;
        #pragma unroll
        for (int j = 0; j < NW; ++j) tot += s_red64[j];
        __syncthreads();
        int n1 = (int)(tot & 0x1FFFFFull);
        int n2 = (int)((tot >> 21) & 0x1FFFFFull);
        int n3 = (int)((tot >> 42) & 0x1FFFFFull);
        if (pair){
            vk |= (n3 >= k) ? (3u << bit) : (n2 >= k) ? (2u << bit)
                 : (n1 >= k) ? (1u << bit) : 0u;
        } else {
            vk |= (n1 >= k) ? (1u << 30) : 0u;
        }
    }

    // ---- strictly-greater count & sum, then loss_c ----
    int ngt = 0; float sgt = 0.0f;
    #pragma unroll
    for (int i = 0; i < PPT; ++i){
        if (rb_[i] > vk){ ++ngt; sgt += __uint_as_float(rb_[i]); }
    }
    #pragma unroll
    for (int off = 32; off > 0; off >>= 1){
        ngt += __shfl_xor(ngt, off);
        sgt += __shfl_xor(sgt, off);
    }
    if (lane == 0){ s_redi[wid] = ngt; s_redf[wid] = sgt; }
    __syncthreads();
    int ngt_tot = 0; float sgt_tot = 0.0f;
    #pragma unroll
    for (int j = 0; j < NW; ++j){ ngt_tot += s_redi[j]; sgt_tot += s_redf[j]; }

    if (tid == 0){
        float lossc = sumce_tot;
        if (k > 0)
            lossc += sgt_tot + (float)(k - ngt_tot) * __uint_as_float(vk);
        out_part[b * 4 + 0] = lossl_tot;
        out_part[b * 4 + 1] = lossc;
        out_part[b * 4 + 2] = (float)npos_tot;
    }
}

__global__ void mbox_final(const float* __restrict__ part, float* __restrict__ out){
    int tid = threadIdx.x;           // 256 threads
    int lane = tid & 63, wid = tid >> 6;
    float ll = part[tid * 4 + 0];
    float lc = part[tid * 4 + 1];
    float np_ = part[tid * 4 + 2];
    #pragma unroll
    for (int off = 32; off > 0; off >>= 1){
        ll  += __shfl_xor(ll,  off);
        lc  += __shfl_xor(lc,  off);
        np_ += __shfl_xor(np_, off);
    }
    __shared__ float sl[4], sc[4], sn[4];
    if (lane == 0){ sl[wid] = ll; sc[wid] = lc; sn[wid] = np_; }
    __syncthreads();
    if (tid == 0){
        float L = sl[0] + sl[1] + sl[2] + sl[3];
        float C = sc[0] + sc[1] + sc[2] + sc[3];
        float N = sn[0] + sn[1] + sn[2] + sn[3];
        out[0] = L / N;
        out[1] = C / N;
    }
}

extern "C" void kernel_launch(void* const* d_in, const int* in_sizes, int n_in,
                              void* d_out, int out_size, void* d_ws, size_t ws_size,
                              hipStream_t stream){
    const float* loc     = (const float*)d_in[0];
    const float* conf    = (const float*)d_in[1];
    const float* priors  = (const float*)d_in[2];
    const float* targets = (const float*)d_in[3];
    float* part = (float*)d_ws;      // 256*4 floats, written before read
    float* out  = (float*)d_out;     // [loss_l/N, loss_c/N]
    mbox_main<<<NB, NT, 0, stream>>>(loc, conf, priors, targets, part);
    mbox_final<<<1, NB, 0, stream>>>(part, out);
}

// Round 13
// 180.418 us; speedup vs baseline: 1.2664x; 1.2664x over previous
//
#include <hip/hip_runtime.h>

#define NP   8732
#define NOBJ 32
#define NB   256
#define NT   1024
#define PPT  9            // ceil(8732/1024)
#define NW   (NT/64)      // 16 waves

__device__ __forceinline__ float sl1(float d){
    float ad = fabsf(d);
    return ad < 1.0f ? 0.5f * d * d : ad - 0.5f;
}

// r11 post-mortem: ~2.7x VALU inflation is structure-invariant (r3/r9/r11 all);
// wall time tracks hand-counted WORK. Best dataflow = r8's t-outer, priors in
// regs (122us). This round: r8 verbatim EXCEPT Phase-A exact div -> rcp+Newton
// (~25% Phase-A op cut; accepts ulp-tie argmax flips, absmax ~1e-3 expected).
__global__ __attribute__((amdgpu_flat_work_group_size(NT, NT),
                          amdgpu_waves_per_eu(4, 4))) void mbox_main(
    const float* __restrict__ loc_data,   // [B,P,4]
    const float* __restrict__ conf_data,  // [B,P,2]
    const float* __restrict__ priors,     // [P,4] cx,cy,w,h
    const float* __restrict__ targets,    // [B,NOBJ,5] x1,y1,x2,y2,label
    float* __restrict__ out_part)         // [B,4] lossl, lossc, npos, pad
{
    const int b    = blockIdx.x;
    const int tid  = threadIdx.x;
    const int lane = tid & 63;
    const int wid  = tid >> 6;

    __shared__ float s_tx1[NOBJ], s_ty1[NOBJ], s_tx2[NOBJ], s_ty2[NOBJ],
                     s_ta[NOBJ], s_tl[NOBJ];
    __shared__ float s_bto[NP];
    __shared__ unsigned char s_bti[NP];
    __shared__ unsigned long long s_part[NOBJ][NW];  // per-wave per-truth best key
    __shared__ int s_bp[NOBJ];
    __shared__ unsigned long long s_red64[NW];
    __shared__ float s_redf[NW], s_redf2[NW];
    __shared__ int s_redi[NW];

    // ---- load truths ----
    if (tid < NOBJ){
        const float* tp = targets + ((size_t)b * NOBJ + tid) * 5;
        float x1 = tp[0], y1 = tp[1], x2 = tp[2], y2 = tp[3];
        s_tx1[tid] = x1; s_ty1[tid] = y1; s_tx2[tid] = x2; s_ty2[tid] = y2;
        s_ta[tid]  = (x2 - x1) * (y2 - y1);
        s_tl[tid]  = tp[4];
    }
    __syncthreads();

    // ---- load my priors into registers (point form + area) ----
    float px1[PPT], py1[PPT], px2[PPT], py2[PPT], pa[PPT], bto[PPT];
    int   bti[PPT];
    #pragma unroll
    for (int i = 0; i < PPT; ++i){
        int p = tid + i * NT;
        if (p < NP){
            float4 pr = reinterpret_cast<const float4*>(priors)[p];
            float hx = pr.z * 0.5f, hy = pr.w * 0.5f;
            px1[i] = pr.x - hx; py1[i] = pr.y - hy;
            px2[i] = pr.x + hx; py2[i] = pr.y + hy;
            pa[i]  = (px2[i] - px1[i]) * (py2[i] - py1[i]);
        } else {                       // degenerate far box -> iou == 0
            px1[i] = 4e9f; py1[i] = 4e9f; px2[i] = 4e9f; py2[i] = 4e9f;
            pa[i]  = 1.0f;
        }
        bto[i] = -1.0f; bti[i] = 0;
    }

    // ---- Phase A: 32 truths x 9 priors IoU (rcp+Newton), track both argmaxes ----
    #pragma unroll 1
    for (int t = 0; t < NOBJ; ++t){
        float tx1 = s_tx1[t], ty1 = s_ty1[t], tx2 = s_tx2[t], ty2 = s_ty2[t];
        float ta  = s_ta[t];
        float bv = -1.0f; int bp = 0;
        #pragma unroll
        for (int i = 0; i < PPT; ++i){
            float lx = fmaxf(tx1, px1[i]);
            float ly = fmaxf(ty1, py1[i]);
            float rx = fminf(tx2, px2[i]);
            float ry = fminf(ty2, py2[i]);
            float w  = fmaxf(rx - lx, 0.0f);
            float h  = fmaxf(ry - ly, 0.0f);
            float inter = w * h;
            float den   = ta + pa[i] - inter;
            float r     = __builtin_amdgcn_rcpf(den);
            r = r * (2.0f - den * r);                // 1 Newton: ~1ulp quotient
            float iou   = inter * r;
            if (iou > bto[i]){ bto[i] = iou; bti[i] = t; }
            if (iou > bv){ bv = iou; bp = tid + i * NT; }
        }
        // wave reduce: max value, min index on tie (first-occurrence argmax)
        #pragma unroll
        for (int off = 32; off > 0; off >>= 1){
            float ov = __shfl_xor(bv, off);
            int   op = __shfl_xor(bp, off);
            if (ov > bv || (ov == bv && op < bp)){ bv = ov; bp = op; }
        }
        if (lane == 0)
            s_part[t][wid] = ((unsigned long long)__float_as_uint(bv) << 32)
                           | (unsigned)(NP - 1 - bp);
    }

    // ---- store per-prior best to LDS ----
    #pragma unroll
    for (int i = 0; i < PPT; ++i){
        int p = tid + i * NT;
        if (p < NP){
            s_bto[p] = bto[i];
            s_bti[p] = (unsigned char)bti[i];
        }
    }
    __syncthreads();

    // ---- combine per-truth partials, then sequential override ----
    if (tid < NOBJ){
        unsigned long long best = 0ull;
        #pragma unroll
        for (int j = 0; j < NW; ++j){
            unsigned long long v = s_part[tid][j];
            if (v > best) best = v;
        }
        s_bp[tid] = NP - 1 - (int)(best & 0xffffffffu);
    }
    __syncthreads();
    if (tid == 0){
        for (int t = 0; t < NOBJ; ++t){   // ascending: last write wins on dup
            int p = s_bp[t];
            s_bto[p] = 2.0f;
            s_bti[p] = (unsigned char)t;
        }
    }
    __syncthreads();

    // ---- Phase C: ce / loc loss / rank ----
    float lossl = 0.0f, sumce = 0.0f;
    int npos = 0;
    unsigned rb_[PPT];
    #pragma unroll
    for (int i = 0; i < PPT; ++i){
        int p = tid + i * NT;
        float rank = 0.0f;
        if (p < NP){
            float ov = s_bto[p];
            int   t  = s_bti[p];
            bool pos = !(ov < 0.5f);
            float2 c = reinterpret_cast<const float2*>(conf_data)[(size_t)b * NP + p];
            float m   = fmaxf(c.x, c.y);
            float lse = m + logf(expf(c.x - m) + expf(c.y - m));
            if (pos){
                int cls = (int)s_tl[t] + 1;
                float g = (cls >= 1) ? c.y : c.x;
                float ce = lse - g;
                ++npos;
                sumce += ce;
                float4 l  = reinterpret_cast<const float4*>(loc_data)[(size_t)b * NP + p];
                float4 pr = reinterpret_cast<const float4*>(priors)[p];
                float mx1 = s_tx1[t], my1 = s_ty1[t], mx2 = s_tx2[t], my2 = s_ty2[t];
                float gcx = ((mx1 + mx2) * 0.5f - pr.x) / (0.1f * pr.z);
                float gcy = ((my1 + my2) * 0.5f - pr.y) / (0.1f * pr.w);
                float gw  = logf((mx2 - mx1) / pr.z) / 0.2f;
                float gh  = logf((my2 - my1) / pr.w) / 0.2f;
                lossl += sl1(l.x - gcx) + sl1(l.y - gcy)
                       + sl1(l.z - gw)  + sl1(l.w - gh);
                rank = 0.0f;                       // positives zeroed in ranking
            } else {
                rank = lse - c.x;                  // ce with class 0 (>= 0)
            }
        }
        rb_[i] = __float_as_uint(rank);            // rank >= 0 -> bits ordered
    }

    // ---- reduce npos / sumce / lossl (all threads get totals) ----
    #pragma unroll
    for (int off = 32; off > 0; off >>= 1){
        npos  += __shfl_xor(npos,  off);
        sumce += __shfl_xor(sumce, off);
        lossl += __shfl_xor(lossl, off);
    }
    if (lane == 0){ s_redi[wid] = npos; s_redf[wid] = sumce; s_redf2[wid] = lossl; }
    __syncthreads();
    int npos_tot = 0; float sumce_tot = 0.0f, lossl_tot = 0.0f;
    #pragma unroll
    for (int j = 0; j < NW; ++j){
        npos_tot  += s_redi[j];
        sumce_tot += s_redf[j];
        lossl_tot += s_redf2[j];
    }
    __syncthreads();

    // ---- Phase D: k-th largest rank via 2-bit radix binary search ----
    int k = 3 * npos_tot; if (k > NP - 1) k = NP - 1;
    unsigned vk = 0u;
    // bit 30 alone, then 15 pairs (29..0). Counts packed 3x21 bits in u64.
    for (int bit = 30; bit >= 0; bit = (bit == 30) ? 28 : bit - 2){
        unsigned c1, c2, c3;
        bool pair = (bit != 30);
        if (pair){
            c1 = vk | (1u << bit); c2 = vk | (2u << bit); c3 = vk | (3u << bit);
        } else {
            c1 = vk | (1u << 30); c2 = 0xffffffffu; c3 = 0xffffffffu;
        }
        unsigned long long pc = 0ull;
        #pragma unroll
        for (int i = 0; i < PPT; ++i){
            unsigned u = rb_[i];
            pc += (u >= c1) ? 1ull : 0ull;
            pc += (u >= c2) ? (1ull << 21) : 0ull;
            pc += (u >= c3) ? (1ull << 42) : 0ull;
        }
        #pragma unroll
        for (int off = 32; off > 0; off >>= 1)
            pc += __shfl_xor(pc, off);
        if (lane == 0) s_red64[wid] = pc;
        __syncthreads();
        unsigned long long tot = 0ull;
        #pragma unroll
        for (int j = 0; j < NW; ++j) tot += s_red64[j];
        __syncthreads();
        int n1 = (int)(tot & 0x1FFFFFull);
        int n2 = (int)((tot >> 21) & 0x1FFFFFull);
        int n3 = (int)((tot >> 42) & 0x1FFFFFull);
        if (pair){
            vk |= (n3 >= k) ? (3u << bit) : (n2 >= k) ? (2u << bit)
                 : (n1 >= k) ? (1u << bit) : 0u;
        } else {
            vk |= (n1 >= k) ? (1u << 30) : 0u;
        }
    }

    // ---- strictly-greater count & sum, then loss_c ----
    int ngt = 0; float sgt = 0.0f;
    #pragma unroll
    for (int i = 0; i < PPT; ++i){
        if (rb_[i] > vk){ ++ngt; sgt += __uint_as_float(rb_[i]); }
    }
    #pragma unroll
    for (int off = 32; off > 0; off >>= 1){
        ngt += __shfl_xor(ngt, off);
        sgt += __shfl_xor(sgt, off);
    }
    if (lane == 0){ s_redi[wid] = ngt; s_redf[wid] = sgt; }
    __syncthreads();
    int ngt_tot = 0; float sgt_tot = 0.0f;
    #pragma unroll
    for (int j = 0; j < NW; ++j){ ngt_tot += s_redi[j]; sgt_tot += s_redf[j]; }

    if (tid == 0){
        float lossc = sumce_tot;
        if (k > 0)
            lossc += sgt_tot + (float)(k - ngt_tot) * __uint_as_float(vk);
        out_part[b * 4 + 0] = lossl_tot;
        out_part[b * 4 + 1] = lossc;
        out_part[b * 4 + 2] = (float)npos_tot;
    }
}

__global__ void mbox_final(const float* __restrict__ part, float* __restrict__ out){
    int tid = threadIdx.x;           // 256 threads
    int lane = tid & 63, wid = tid >> 6;
    float ll = part[tid * 4 + 0];
    float lc = part[tid * 4 + 1];
    float np_ = part[tid * 4 + 2];
    #pragma unroll
    for (int off = 32; off > 0; off >>= 1){
        ll  += __shfl_xor(ll,  off);
        lc  += __shfl_xor(lc,  off);
        np_ += __shfl_xor(np_, off);
    }
    __shared__ float sl[4], sc[4], sn[4];
    if (lane == 0){ sl[wid] = ll; sc[wid] = lc; sn[wid] = np_; }
    __syncthreads();
    if (tid == 0){
        float L = sl[0] + sl[1] + sl[2] + sl[3];
        float C = sc[0] + sc[1] + sc[2] + sc[3];
        float N = sn[0] + sn[1] + sn[2] + sn[3];
        out[0] = L / N;
        out[1] = C / N;
    }
}

extern "C" void kernel_launch(void* const* d_in, const int* in_sizes, int n_in,
                              void* d_out, int out_size, void* d_ws, size_t ws_size,
                              hipStream_t stream){
    const float* loc     = (const float*)d_in[0];
    const float* conf    = (const float*)d_in[1];
    const float* priors  = (const float*)d_in[2];
    const float* targets = (const float*)d_in[3];
    float* part = (float*)d_ws;      // 256*4 floats, written before read
    float* out  = (float*)d_out;     // [loss_l/N, loss_c/N]
    mbox_main<<<NB, NT, 0, stream>>>(loc, conf, priors, targets, part);
    mbox_final<<<1, NB, 0, stream>>>(part, out);
}